// Round 2
// baseline (46.221 us; speedup 1.0000x reference)
//
#include <hip/hip_runtime.h>
#include <hip/hip_bf16.h>

#define NRAYS 8192
#define NSAMP 173
#define LASTI 172

__device__ __forceinline__ float wave_sum64(float v) {
#pragma unroll
    for (int off = 32; off > 0; off >>= 1) v += __shfl_xor(v, off, 64);
    return v;
}

__device__ __forceinline__ float softplus_f(float x) {
    if (x > 15.f) return x;
    return __logf(1.f + __expf(x));
}
__device__ __forceinline__ float sigmoid_f(float x) {
    return 1.f / (1.f + __expf(-x));
}

__launch_bounds__(256)
__global__ void render_kernel(
    const float* __restrict__ rays,
    const float* __restrict__ Wd1,
    const float* __restrict__ bd1,
    const float* __restrict__ Wd2,
    const float* __restrict__ bd2,
    const float* __restrict__ Wapp,
    const float* __restrict__ Wa1,
    const float* __restrict__ ba1,
    const float* __restrict__ Wa2,
    const float* __restrict__ ba2,
    const float* __restrict__ Wsf,
    const float* __restrict__ Wsm,
    const float* __restrict__ bsm,
    const float* __restrict__ Wi,
    const int* __restrict__ whitebg_p,
    float* __restrict__ out,
    float* __restrict__ wsdist)
{
    // f32 staged weights (block-level)
    __shared__ float4 qd[64];      // (Wd1[0][u], Wd1[1][u], Wd1[2][u], bd1[u])
    __shared__ float  wd2s[64];    // Wd2[u]
    __shared__ float  wacf[64 * 4];// Wac[u*4+m] = (Wapp @ Wa1[:27])[m][u]
    __shared__ float4 wa2q[64];    // (Wa2[u][0..2], 0)
    __shared__ float  wscs[60];    // (Wsf@Wsm)[m*20+s]
    __shared__ float  bsms[20];
    __shared__ float  wis[48];     // Wi[m*16+k]
    __shared__ float  bd2s;
    __shared__ float  ba2s[3];
    __shared__ float4 qaw[4][64];  // per-wave: (Wac cols, dconst[u])

    const int t = threadIdx.x;

    if (t < 64) {
        qd[t] = make_float4(Wd1[t], Wd1[64 + t], Wd1[128 + t], bd1[t]);
        wd2s[t] = Wd2[t];
    } else if (t < 128) {
        int u = t - 64;
        wa2q[u] = make_float4(Wa2[3 * u], Wa2[3 * u + 1], Wa2[3 * u + 2], 0.f);
    }
    if (t < 192) {
        int m = t >> 6, u = t & 63;
        float s = 0.f;
        for (int j = 0; j < 27; ++j) s = fmaf(Wapp[m * 27 + j], Wa1[j * 64 + u], s);
        wacf[u * 4 + m] = s;
    } else {
        for (int job = t - 192; job < 132; job += 64) {
            if (job < 60) {
                int m = job / 20, sidx = job % 20;
                float s = 0.f;
                for (int k = 0; k < 32; ++k) s = fmaf(Wsf[m * 32 + k], Wsm[k * 20 + sidx], s);
                wscs[job] = s;
            } else if (job < 80) {
                bsms[job - 60] = bsm[job - 60];
            } else if (job < 128) {
                wis[job - 80] = Wi[job - 80];
            } else if (job == 128) {
                bd2s = bd2[0];
            } else {
                ba2s[job - 129] = ba2[job - 129];
            }
        }
    }
    __syncthreads();

    const int wid = t >> 6, lane = t & 63;
    const int r = blockIdx.x * 4 + wid;

    const float o0 = rays[r * 6 + 0], o1 = rays[r * 6 + 1], o2 = rays[r * 6 + 2];
    const float d0 = rays[r * 6 + 3], d1 = rays[r * 6 + 4], d2 = rays[r * 6 + 5];

    // t_min -- replicate numpy f32 rounding exactly (knife-edge: sample 0 on box face)
    float tm;
    {
        float v0 = (d0 == 0.f) ? 1e-6f : d0;
        float v1 = (d1 == 0.f) ? 1e-6f : d1;
        float v2 = (d2 == 0.f) ? 1e-6f : d2;
        float a0 = __fdiv_rn(__fsub_rn(1.5f, o0), v0), b0 = __fdiv_rn(__fsub_rn(-1.5f, o0), v0);
        float a1 = __fdiv_rn(__fsub_rn(1.5f, o1), v1), b1 = __fdiv_rn(__fsub_rn(-1.5f, o1), v1);
        float a2 = __fdiv_rn(__fsub_rn(1.5f, o2), v2), b2 = __fdiv_rn(__fsub_rn(-1.5f, o2), v2);
        float m0 = fminf(a0, b0), m1 = fminf(a1, b1), m2 = fminf(a2, b2);
        tm = fmaxf(fmaxf(m0, m1), m2);
        tm = fminf(fmaxf(tm, 0.05f), 6.0f);
    }

    // per-ray appearance constants: qaw[u] = (Wac[0][u], Wac[1][u], Wac[2][u], d@Wa1[27:30][u] + ba1[u])
    {
        float4 q;
        q.x = wacf[lane * 4 + 0];
        q.y = wacf[lane * 4 + 1];
        q.z = wacf[lane * 4 + 2];
        float dc = ba1[lane];
        dc = fmaf(d0, Wa1[27 * 64 + lane], dc);
        dc = fmaf(d1, Wa1[28 * 64 + lane], dc);
        dc = fmaf(d2, Wa1[29 * 64 + lane], dc);
        q.w = dc;
        qaw[wid][lane] = q;
    }
    __syncthreads();

    const float STEPF = (float)(3.0 / 299.001 * 3.0);

    float aR0 = 0.f, aR1 = 0.f, aR2 = 0.f;       // sum w * rgb
    float aS0 = 0.f, aS1 = 0.f, aS2 = 0.f;       // sum masked w * xyzn
    float aSw = 0.f;                             // sum masked w
    float aD = 0.f, aLu = 0.f, aLb = 0.f;        // depth, loss_uni, loss_bi
    float Tc = 1.f, Wcar = 0.f, WMc = 0.f;       // carries: transmittance, cumsum w, cumsum wm

    for (int c = 0; c < 3; ++c) {
        int i = (c << 6) + lane;
        bool valid = i < NSAMP;
        float z = __fadd_rn(tm, __fmul_rn((float)i, STEPF));
        float x0 = __fadd_rn(o0, __fmul_rn(d0, z));
        float x1 = __fadd_rn(o1, __fmul_rn(d1, z));
        float x2 = __fadd_rn(o2, __fmul_rn(d2, z));
        bool inbox = valid && (x0 >= -1.5f) && (x0 <= 1.5f) && (x1 >= -1.5f) && (x1 <= 1.5f) &&
                     (x2 >= -1.5f) && (x2 <= 1.5f);
        if (__ballot(inbox) == 0ull) continue;  // whole chunk out of box: zero weight, carries unchanged

        float xn0 = x0 * (2.f / 3.f), xn1 = x1 * (2.f / 3.f), xn2 = x2 * (2.f / 3.f);

        // density MLP: sp = bd2 + sum_u relu(xyzn . Wd1[:,u] + bd1[u]) * Wd2[u]
        float sp = bd2s;
#pragma unroll 16
        for (int u = 0; u < 64; ++u) {
            float4 q = qd[u];
            float h = fmaf(xn0, q.x, fmaf(xn1, q.y, fmaf(xn2, q.z, q.w)));
            h = fmaxf(h, 0.f);
            sp = fmaf(h, wd2s[u], sp);
        }
        float sigma = inbox ? softplus_f(sp) : 0.f;

        float znext = __fadd_rn(tm, __fmul_rn((float)(i + 1), STEPF));
        float dist = (i < LASTI) ? __fsub_rn(znext, z) : 0.f;  // numpy: z[i+1]-z[i]
        float alpha = 1.f - __expf(-sigma * dist * 25.f);
        float f = 1.f - alpha + 1e-10f;

        // inclusive product scan of f across 64 lanes
        float p = f;
#pragma unroll
        for (int off = 1; off < 64; off <<= 1) {
            float n = __shfl_up(p, off, 64);
            if (lane >= off) p *= n;
        }
        float pex = __shfl_up(p, 1, 64);
        if (lane == 0) pex = 1.f;
        float T = Tc * pex;
        float w = alpha * T;

        float zlast2 = __fadd_rn(tm, __fmul_rn(171.f, STEPF));
        float mid = (i < LASTI) ? 0.5f * __fadd_rn(z, znext) : zlast2;
        float wm = w * mid;

        // inclusive sum scans of w and wm
        float sw = w, swm = wm;
#pragma unroll
        for (int off = 1; off < 64; off <<= 1) {
            float n1 = __shfl_up(sw, off, 64);
            float n2 = __shfl_up(swm, off, 64);
            if (lane >= off) { sw += n1; swm += n2; }
        }
        float wex = __shfl_up(sw, 1, 64);
        float wmex = __shfl_up(swm, 1, 64);
        if (lane == 0) { wex = 0.f; wmex = 0.f; }

        aLb += wm * (Wcar + wex) - w * (WMc + wmex);
        aLu = fmaf(dist * w, w, aLu);
        aD = fmaf(w, z, aD);

        Tc *= __shfl(p, 63, 64);
        Wcar += __shfl(sw, 63, 64);
        WMc += __shfl(swm, 63, 64);

        // appearance (only where w > W_THRES)
        float wapp = (w > 1e-4f) ? w : 0.f;
        if (__ballot(wapp > 0.f) != 0ull) {
            float c0 = 0.f, c1 = 0.f, c2 = 0.f;
#pragma unroll 16
            for (int u = 0; u < 64; ++u) {
                float4 q = qaw[wid][u];
                float h = fmaf(xn0, q.x, fmaf(xn1, q.y, fmaf(xn2, q.z, q.w)));
                h = fmaxf(h, 0.f);
                float4 a2 = wa2q[u];
                c0 = fmaf(h, a2.x, c0);
                c1 = fmaf(h, a2.y, c1);
                c2 = fmaf(h, a2.z, c2);
            }
            float r0 = sigmoid_f(c0 + ba2s[0]);
            float r1 = sigmoid_f(c1 + ba2s[1]);
            float r2 = sigmoid_f(c2 + ba2s[2]);
            aR0 = fmaf(wapp, r0, aR0);
            aR1 = fmaf(wapp, r1, aR1);
            aR2 = fmaf(wapp, r2, aR2);
            aS0 = fmaf(wapp, xn0, aS0);
            aS1 = fmaf(wapp, xn1, aS1);
            aS2 = fmaf(wapp, xn2, aS2);
            aSw += wapp;
        }

        if (Tc < 1e-8f) break;  // all later weights < 1e-8 << W_THRES
    }

    // wave reductions
    aR0 = wave_sum64(aR0); aR1 = wave_sum64(aR1); aR2 = wave_sum64(aR2);
    aS0 = wave_sum64(aS0); aS1 = wave_sum64(aS1); aS2 = wave_sum64(aS2);
    aSw = wave_sum64(aSw);
    aD = wave_sum64(aD);
    aLu = wave_sum64(aLu);
    aLb = wave_sum64(aLb);

    float opac = Wcar;  // uniform (came from shfl broadcast)
    int wb = *whitebg_p;
    float bg = wb ? (1.f - opac) : 0.f;

    float* out_rgb = out;
    float* out_sem = out + 24576;
    float* out_inst = out + 188416;
    float* out_dep = out + 319488;

    if (lane < 3) {
        float rv = (lane == 0 ? aR0 : (lane == 1 ? aR1 : aR2)) + bg;
        rv = fminf(fmaxf(rv, 0.f), 1.f);
        out_rgb[r * 3 + lane] = rv;
    }
    if (lane < 20) {
        float sv = aS0 * wscs[lane] + aS1 * wscs[20 + lane] + aS2 * wscs[40 + lane] + aSw * bsms[lane];
        out_sem[r * 20 + lane] = sv;
    }
    if (lane < 16) {
        float iv = aS0 * wis[lane] + aS1 * wis[16 + lane] + aS2 * wis[32 + lane];
        out_inst[r * 16 + lane] = iv;
    }
    if (lane == 0) {
        out_dep[r] = aD;
        wsdist[r] = aLu * (1.f / 3.f) + 2.f * aLb;
    }
}

__global__ void reduce_dist_kernel(const float* __restrict__ ws, float* __restrict__ out) {
    __shared__ float sm[256];
    int t = threadIdx.x;
    float a = 0.f;
    for (int i = t; i < NRAYS; i += 256) a += ws[i];
    sm[t] = a;
    __syncthreads();
    for (int st = 128; st > 0; st >>= 1) {
        if (t < st) sm[t] += sm[t + st];
        __syncthreads();
    }
    if (t == 0) out[0] = sm[0] * (1.f / (float)NRAYS);
}

extern "C" void kernel_launch(void* const* d_in, const int* in_sizes, int n_in,
                              void* d_out, int out_size, void* d_ws, size_t ws_size,
                              hipStream_t stream) {
    const float* rays = (const float*)d_in[0];
    const float* Wd1  = (const float*)d_in[1];
    const float* bd1  = (const float*)d_in[2];
    const float* Wd2  = (const float*)d_in[3];
    const float* bd2  = (const float*)d_in[4];
    const float* Wapp = (const float*)d_in[5];
    const float* Wa1  = (const float*)d_in[6];
    const float* ba1  = (const float*)d_in[7];
    const float* Wa2  = (const float*)d_in[8];
    const float* ba2  = (const float*)d_in[9];
    const float* Wsf  = (const float*)d_in[10];
    const float* Wsm  = (const float*)d_in[11];
    const float* bsm  = (const float*)d_in[12];
    const float* Wi   = (const float*)d_in[13];
    const int* wb     = (const int*)d_in[15];

    float* out = (float*)d_out;
    float* ws = (float*)d_ws;  // 8192 f32 = 32 KB

    render_kernel<<<NRAYS / 4, 256, 0, stream>>>(rays, Wd1, bd1, Wd2, bd2, Wapp, Wa1, ba1,
                                                 Wa2, ba2, Wsf, Wsm, bsm, Wi, wb, out, ws);
    reduce_dist_kernel<<<1, 256, 0, stream>>>(ws, out + 327680);
}

// Round 3
// 37.100 us; speedup vs baseline: 1.2459x; 1.2459x over previous
//
#include <hip/hip_runtime.h>

#define NRAYS 8192
#define NSAMP 173
#define LASTI 172

__device__ __forceinline__ float wave_sum64(float v) {
#pragma unroll
    for (int off = 32; off > 0; off >>= 1) v += __shfl_xor(v, off, 64);
    return v;
}

__device__ __forceinline__ float softplus_f(float x) {
    if (x > 15.f) return x;
    return __logf(1.f + __expf(x));
}
__device__ __forceinline__ float sigmoid_f(float x) {
    return 1.f / (1.f + __expf(-x));
}

// ---- prep: fold all weight tables into d_ws (f32), once per launch ----
// layout (float offsets):
//   0    qdpk float4[64]  (Wd1 cols + bd1)
//   256  wd2[64]
//   320  dpack float4[64] (Wa1 rows 27..29 + ba1)   [per-ray dconst inputs]
//   576  wac0[64] 640 wac1[64] 704 wac2[64]         (Wapp @ Wa1[:27])
//   768  wa20[64] 832 wa21[64] 896 wa22[64]         (Wa2 columns)
//   960  wscs[60] 1020 bsm[20] 1040 wi[48] 1088 bd2 1089 ba2[3]
__global__ void prep_kernel(
    const float* __restrict__ Wd1, const float* __restrict__ bd1,
    const float* __restrict__ Wd2, const float* __restrict__ bd2,
    const float* __restrict__ Wapp, const float* __restrict__ Wa1,
    const float* __restrict__ ba1, const float* __restrict__ Wa2,
    const float* __restrict__ ba2, const float* __restrict__ Wsf,
    const float* __restrict__ Wsm, const float* __restrict__ bsm,
    const float* __restrict__ Wi, float* __restrict__ prep)
{
    const int t = threadIdx.x;
    if (t < 64) {
        ((float4*)prep)[t] = make_float4(Wd1[t], Wd1[64 + t], Wd1[128 + t], bd1[t]);
        prep[256 + t] = Wd2[t];
        ((float4*)(prep + 320))[t] =
            make_float4(Wa1[27 * 64 + t], Wa1[28 * 64 + t], Wa1[29 * 64 + t], ba1[t]);
    } else if (t < 128) {
        int u = t - 64;
        prep[768 + u] = Wa2[3 * u];
        prep[832 + u] = Wa2[3 * u + 1];
        prep[896 + u] = Wa2[3 * u + 2];
    } else if (t < 192) {
        int u = t - 128;
        float s0 = 0.f, s1 = 0.f, s2 = 0.f;
        for (int j = 0; j < 27; ++j) {
            float w = Wa1[j * 64 + u];
            s0 = fmaf(Wapp[j], w, s0);
            s1 = fmaf(Wapp[27 + j], w, s1);
            s2 = fmaf(Wapp[54 + j], w, s2);
        }
        prep[576 + u] = s0;
        prep[640 + u] = s1;
        prep[704 + u] = s2;
    } else {
        for (int job = t - 192; job < 132; job += 64) {
            if (job < 60) {
                int m = job / 20, s = job % 20;
                float a = 0.f;
                for (int k = 0; k < 32; ++k) a = fmaf(Wsf[m * 32 + k], Wsm[k * 20 + s], a);
                prep[960 + job] = a;
            } else if (job < 80) {
                prep[1020 + (job - 60)] = bsm[job - 60];
            } else if (job < 128) {
                prep[1040 + (job - 80)] = Wi[job - 80];
            } else if (job == 128) {
                prep[1088] = bd2[0];
            } else {
                prep[1089 + (job - 129)] = ba2[job - 129];
            }
        }
    }
}

__launch_bounds__(256)
__global__ void render_kernel(
    const float* __restrict__ rays,
    const float* __restrict__ prep,
    const int* __restrict__ whitebg_p,
    float* __restrict__ out,
    float* __restrict__ wsdist)
{
    const int t = threadIdx.x;
    const int wid = t >> 6, lane = t & 63;
    const int r = blockIdx.x * 4 + wid;

    const float4* __restrict__ qdT = (const float4*)prep;
    const float* __restrict__ wd2T = prep + 256;
    const float4* __restrict__ dpT = (const float4*)(prep + 320);
    const float* __restrict__ wac0T = prep + 576;
    const float* __restrict__ wac1T = prep + 640;
    const float* __restrict__ wac2T = prep + 704;
    const float* __restrict__ wa20T = prep + 768;
    const float* __restrict__ wa21T = prep + 832;
    const float* __restrict__ wa22T = prep + 896;

    // ray (wave-uniform -> scalar loads)
    const float o0 = rays[r * 6 + 0], o1 = rays[r * 6 + 1], o2 = rays[r * 6 + 2];
    const float d0 = rays[r * 6 + 3], d1 = rays[r * 6 + 4], d2 = rays[r * 6 + 5];

    // t_min -- replicate numpy f32 rounding exactly (knife-edge: sample 0 on box face)
    float tm;
    {
        float v0 = (d0 == 0.f) ? 1e-6f : d0;
        float v1 = (d1 == 0.f) ? 1e-6f : d1;
        float v2 = (d2 == 0.f) ? 1e-6f : d2;
        float a0 = __fdiv_rn(__fsub_rn(1.5f, o0), v0), b0 = __fdiv_rn(__fsub_rn(-1.5f, o0), v0);
        float a1 = __fdiv_rn(__fsub_rn(1.5f, o1), v1), b1 = __fdiv_rn(__fsub_rn(-1.5f, o1), v1);
        float a2 = __fdiv_rn(__fsub_rn(1.5f, o2), v2), b2 = __fdiv_rn(__fsub_rn(-1.5f, o2), v2);
        float m0 = fminf(a0, b0), m1 = fminf(a1, b1), m2 = fminf(a2, b2);
        tm = fmaxf(fmaxf(m0, m1), m2);
        tm = fminf(fmaxf(tm, 0.05f), 6.0f);
    }

    // per-ray appearance constant for unit==lane, kept lane-distributed
    float ddc;
    {
        float4 dp = dpT[lane];
        ddc = fmaf(d2, dp.z, fmaf(d1, dp.y, fmaf(d0, dp.x, dp.w)));
    }

    const float bd2c = prep[1088];
    const float ba2c0 = prep[1089], ba2c1 = prep[1090], ba2c2 = prep[1091];

    const float STEPF = (float)(3.0 / 299.001 * 3.0);

    float aR0 = 0.f, aR1 = 0.f, aR2 = 0.f;       // sum w * rgb
    float aS0 = 0.f, aS1 = 0.f, aS2 = 0.f;       // sum masked w * xyzn
    float aSw = 0.f;                             // sum masked w
    float aD = 0.f, aLu = 0.f, aLb = 0.f;        // depth, loss_uni, loss_bi
    float Tc = 1.f, Wcar = 0.f, WMc = 0.f;       // carries

    for (int c = 0; c < 3; ++c) {
        int i = (c << 6) + lane;
        bool valid = i < NSAMP;
        float z = __fadd_rn(tm, __fmul_rn((float)i, STEPF));
        float x0 = __fadd_rn(o0, __fmul_rn(d0, z));
        float x1 = __fadd_rn(o1, __fmul_rn(d1, z));
        float x2 = __fadd_rn(o2, __fmul_rn(d2, z));
        bool inbox = valid && (x0 >= -1.5f) && (x0 <= 1.5f) && (x1 >= -1.5f) && (x1 <= 1.5f) &&
                     (x2 >= -1.5f) && (x2 <= 1.5f);
        if (__ballot(inbox) == 0ull) continue;

        float xn0 = x0 * (2.f / 3.f), xn1 = x1 * (2.f / 3.f), xn2 = x2 * (2.f / 3.f);

        // density MLP (weights via uniform/scalar loads)
        float sp = bd2c;
#pragma unroll
        for (int u = 0; u < 64; ++u) {
            float4 q = qdT[u];
            float h = fmaf(xn0, q.x, fmaf(xn1, q.y, fmaf(xn2, q.z, q.w)));
            sp = fmaf(fmaxf(h, 0.f), wd2T[u], sp);
        }
        float sigma = inbox ? softplus_f(sp) : 0.f;

        float znext = __fadd_rn(tm, __fmul_rn((float)(i + 1), STEPF));
        float dist = (i < LASTI) ? __fsub_rn(znext, z) : 0.f;
        float alpha = 1.f - __expf(-sigma * dist * 25.f);
        float f = 1.f - alpha + 1e-10f;

        // inclusive product scan of f
        float p = f;
#pragma unroll
        for (int off = 1; off < 64; off <<= 1) {
            float n = __shfl_up(p, off, 64);
            if (lane >= off) p *= n;
        }
        float pex = __shfl_up(p, 1, 64);
        if (lane == 0) pex = 1.f;
        float T = Tc * pex;
        float w = alpha * T;

        float zlast2 = __fadd_rn(tm, __fmul_rn(171.f, STEPF));
        float mid = (i < LASTI) ? 0.5f * __fadd_rn(z, znext) : zlast2;
        float wm = w * mid;

        // inclusive sum scans of w, wm
        float sw = w, swm = wm;
#pragma unroll
        for (int off = 1; off < 64; off <<= 1) {
            float n1 = __shfl_up(sw, off, 64);
            float n2 = __shfl_up(swm, off, 64);
            if (lane >= off) { sw += n1; swm += n2; }
        }
        float wex = __shfl_up(sw, 1, 64);
        float wmex = __shfl_up(swm, 1, 64);
        if (lane == 0) { wex = 0.f; wmex = 0.f; }

        aLb += wm * (Wcar + wex) - w * (WMc + wmex);
        aLu = fmaf(dist * w, w, aLu);
        aD = fmaf(w, z, aD);

        Tc *= __shfl(p, 63, 64);
        Wcar += __shfl(sw, 63, 64);
        WMc += __shfl(swm, 63, 64);

        // appearance (only where w > W_THRES)
        float wapp = (w > 1e-4f) ? w : 0.f;
        if (__ballot(wapp > 0.f) != 0ull) {
            float c0 = 0.f, c1 = 0.f, c2 = 0.f;
#pragma unroll
            for (int u = 0; u < 64; ++u) {
                float dcu = __int_as_float(__builtin_amdgcn_readlane(__float_as_int(ddc), u));
                float h = fmaf(xn0, wac0T[u], fmaf(xn1, wac1T[u], fmaf(xn2, wac2T[u], dcu)));
                h = fmaxf(h, 0.f);
                c0 = fmaf(h, wa20T[u], c0);
                c1 = fmaf(h, wa21T[u], c1);
                c2 = fmaf(h, wa22T[u], c2);
            }
            float r0 = sigmoid_f(c0 + ba2c0);
            float r1 = sigmoid_f(c1 + ba2c1);
            float r2 = sigmoid_f(c2 + ba2c2);
            aR0 = fmaf(wapp, r0, aR0);
            aR1 = fmaf(wapp, r1, aR1);
            aR2 = fmaf(wapp, r2, aR2);
            aS0 = fmaf(wapp, xn0, aS0);
            aS1 = fmaf(wapp, xn1, aS1);
            aS2 = fmaf(wapp, xn2, aS2);
            aSw += wapp;
        }

        if (Tc < 1e-8f) break;  // all later weights < 1e-8 << W_THRES
    }

    // wave reductions
    aR0 = wave_sum64(aR0); aR1 = wave_sum64(aR1); aR2 = wave_sum64(aR2);
    aS0 = wave_sum64(aS0); aS1 = wave_sum64(aS1); aS2 = wave_sum64(aS2);
    aSw = wave_sum64(aSw);
    aD = wave_sum64(aD);
    aLu = wave_sum64(aLu);
    aLb = wave_sum64(aLb);

    float opac = Wcar;
    int wb = *whitebg_p;
    float bg = wb ? (1.f - opac) : 0.f;

    float* out_rgb = out;
    float* out_sem = out + 24576;
    float* out_inst = out + 188416;
    float* out_dep = out + 319488;

    if (lane < 3) {
        float rv = (lane == 0 ? aR0 : (lane == 1 ? aR1 : aR2)) + bg;
        rv = fminf(fmaxf(rv, 0.f), 1.f);
        out_rgb[r * 3 + lane] = rv;
    }
    if (lane < 20) {
        float sv = aS0 * prep[960 + lane] + aS1 * prep[980 + lane] + aS2 * prep[1000 + lane] +
                   aSw * prep[1020 + lane];
        out_sem[r * 20 + lane] = sv;
    }
    if (lane < 16) {
        float iv = aS0 * prep[1040 + lane] + aS1 * prep[1056 + lane] + aS2 * prep[1072 + lane];
        out_inst[r * 16 + lane] = iv;
    }
    if (lane == 0) {
        out_dep[r] = aD;
        wsdist[r] = aLu * (1.f / 3.f) + 2.f * aLb;
    }
}

__global__ void reduce_dist_kernel(const float* __restrict__ ws, float* __restrict__ out) {
    __shared__ float sm[256];
    int t = threadIdx.x;
    float a = 0.f;
    const float4* w4 = (const float4*)ws;
    for (int i = t; i < NRAYS / 4; i += 256) {
        float4 v = w4[i];
        a += (v.x + v.y) + (v.z + v.w);
    }
    sm[t] = a;
    __syncthreads();
    for (int st = 128; st > 0; st >>= 1) {
        if (t < st) sm[t] += sm[t + st];
        __syncthreads();
    }
    if (t == 0) out[0] = sm[0] * (1.f / (float)NRAYS);
}

extern "C" void kernel_launch(void* const* d_in, const int* in_sizes, int n_in,
                              void* d_out, int out_size, void* d_ws, size_t ws_size,
                              hipStream_t stream) {
    const float* rays = (const float*)d_in[0];
    const float* Wd1  = (const float*)d_in[1];
    const float* bd1  = (const float*)d_in[2];
    const float* Wd2  = (const float*)d_in[3];
    const float* bd2  = (const float*)d_in[4];
    const float* Wapp = (const float*)d_in[5];
    const float* Wa1  = (const float*)d_in[6];
    const float* ba1  = (const float*)d_in[7];
    const float* Wa2  = (const float*)d_in[8];
    const float* ba2  = (const float*)d_in[9];
    const float* Wsf  = (const float*)d_in[10];
    const float* Wsm  = (const float*)d_in[11];
    const float* bsm  = (const float*)d_in[12];
    const float* Wi   = (const float*)d_in[13];
    const int* wb     = (const int*)d_in[15];

    float* out = (float*)d_out;
    float* prep = (float*)d_ws;          // 1092 floats of folded tables
    float* wsd = prep + 2048;            // 8192 floats of per-ray dist values

    prep_kernel<<<1, 256, 0, stream>>>(Wd1, bd1, Wd2, bd2, Wapp, Wa1, ba1, Wa2, ba2,
                                       Wsf, Wsm, bsm, Wi, prep);
    render_kernel<<<NRAYS / 4, 256, 0, stream>>>(rays, prep, wb, out, wsd);
    reduce_dist_kernel<<<1, 256, 0, stream>>>(wsd, out + 327680);
}